// Round 1
// baseline (1501.557 us; speedup 1.0000x reference)
//
#include <hip/hip_runtime.h>

#define N_NODES 20000
#define CW_FLOATS 1024                 // 729 used, padded to 4 KiB
#define WCB_FLOATS (3*9*30*64)         // 51840 = repacked W_chem
#define NAB_FLOATS (N_NODES*32)        // 30 used per node, padded to 32

// ---------------------------------------------------------------------------
// Compile-time sparsity pattern of the combined 9x9x9 real-Wigner table.
// Derived from exact Gaunt-integral selection rules (phi-harmonic matching +
// theta parity); any entry excluded here is mathematically zero. Values come
// from the device-computed table (init kernel) so e3nn sign conventions are
// reproduced exactly. 83 entries, grouped by L (the u / l1 index).
// ---------------------------------------------------------------------------
constexpr int ENT_OFF[10] = {0, 9, 19, 27, 37, 45, 55, 65, 75, 83};
constexpr int ENT_M[83] = {
  0,1,2,3,4,5,6,7,8,            // L=0: diagonal (0,l,l) paths
  0,1,3,2,1,1,4,5,6,8,          // L=1
  0,2,1,3,2,5,7,6,              // L=2
  0,3,1,2,3,3,4,7,6,8,          // L=3
  0,4,1,3,6,4,5,7,              // L=4
  0,5,1,2,6,5,5,8,4,7,          // L=5
  0,6,1,2,3,6,5,7,4,8,          // L=6
  0,7,2,3,6,7,7,8,4,5,          // L=7
  0,8,1,3,6,8,5,7               // L=8
};
constexpr int ENT_S[83] = {
  0,1,2,3,4,5,6,7,8,
  1,0,4,5,6,8,3,2,1,1,
  2,0,5,7,6,1,3,2,
  3,0,4,7,6,8,1,2,3,3,
  4,0,3,1,4,6,7,5,
  5,0,2,1,5,6,8,5,7,4,
  6,0,1,2,3,6,5,7,4,8,
  7,0,3,2,7,6,8,7,5,4,
  8,0,1,3,8,6,5,7
};

// ---------------------------------------------------------------------------
// Init kernel: fp64 replication of the reference's Wigner-3j construction
// (CG coefficients + complex->real basis change), plus W_chem repack and the
// scrambled node_attr ("nab") precompute.
// ---------------------------------------------------------------------------
struct cplx { double re, im; };
__device__ inline cplx cmul(cplx a, cplx b){ return {a.re*b.re - a.im*b.im, a.re*b.im + a.im*b.re}; }

__device__ inline double factd(int n){ double r = 1.0; for (int i = 2; i <= n; ++i) r *= (double)i; return r; }

__device__ double cg_coeff(int j1,int m1,int j2,int m2,int j3,int m3){
  if (m3 != m1 + m2) return 0.0;
  int vmin = -j1 + j2 + m3;
  if (-j1 + m1 > vmin) vmin = -j1 + m1;
  if (vmin < 0) vmin = 0;
  int vmax = j2 + j3 + m1;
  if (j3 - j1 + j2 < vmax) vmax = j3 - j1 + j2;
  if (j3 + m3 < vmax) vmax = j3 + m3;
  double c = sqrt((double)(2*j3+1) *
      (factd(j3+j1-j2)*factd(j3-j1+j2)*factd(j1+j2-j3)*factd(j3+m3)*factd(j3-m3)) /
      (factd(j1+j2+j3+1)*factd(j1-m1)*factd(j1+m1)*factd(j2-m2)*factd(j2+m2)));
  double s = 0.0;
  for (int v = vmin; v <= vmax; ++v){
    double t = (factd(j2+j3+m1-v)*factd(j1-m1+v)) /
               (factd(v)*factd(j3-j1+j2-v)*factd(j3+m3-v)*factd(v+j1-j2-m3));
    s += ((v + j2 + m2) & 1) ? -t : t;
  }
  return c * s;
}

__device__ cplx qmat(int l, int r, int c){
  cplx v = {0.0, 0.0};
  const double is2 = 0.70710678118654752440;
  const int m = r - l;
  if (m < 0){
    if (c == 2*l - r)      v = { is2, 0.0 };
    else if (c == r)       v = { 0.0, -is2 };
  } else if (m == 0){
    if (c == l)            v = { 1.0, 0.0 };
  } else {
    const double sg = (m & 1) ? -1.0 : 1.0;
    if (c == r)            v = { sg*is2, 0.0 };
    else if (c == 2*l - r) v = { 0.0, sg*is2 };
  }
  if (l == 1)      v = { v.im, -v.re };   // * (-i)
  else if (l == 2) v = { -v.re, -v.im };  // * (-i)^2 = -1
  return v;
}

__global__ void nn3b_init_kernel(const float* __restrict__ node_attr,
                                 const float* __restrict__ W_chem,
                                 float* __restrict__ cw,
                                 float* __restrict__ wcB,
                                 float* __restrict__ nab)
{
  const int t = blockIdx.x * 256 + threadIdx.x;

  // Job A: combined Wigner table (729 entries; <=8 effective CG terms each
  // because every q-column has <=2 nonzeros).
  if (t < CW_FLOATS){
    float val = 0.0f;
    if (t < 729){
      const int S = t % 9, M = (t / 9) % 9, L = t / 81;
      const int l1 = (L==0)?0:((L<4)?1:2);
      const int l2 = (M==0)?0:((M<4)?1:2);
      const int l3 = (S==0)?0:((S<4)?1:2);
      const int a  = L - ((l1==0)?0:((l1==1)?1:4));
      const int b  = M - ((l2==0)?0:((l2==1)?1:4));
      const int cc = S - ((l3==0)?0:((l3==1)?1:4));
      const int lo = (l1 > l2) ? l1 - l2 : l2 - l1;
      if (l3 >= lo && l3 <= l1 + l2 && (((l1 + l2 + l3) & 1) == 0)){
        cplx acc = {0.0, 0.0};
        for (int i = 0; i < 2*l1+1; ++i){
          cplx q1 = qmat(l1, i, a);
          if (q1.re == 0.0 && q1.im == 0.0) continue;
          for (int k = 0; k < 2*l2+1; ++k){
            cplx q2 = qmat(l2, k, b);
            if (q2.re == 0.0 && q2.im == 0.0) continue;
            cplx q12 = cmul(q1, q2);
            for (int n = 0; n < 2*l3+1; ++n){
              cplx q3 = qmat(l3, n, cc);
              if (q3.re == 0.0 && q3.im == 0.0) continue;
              double cg = cg_coeff(l1, i-l1, l2, k-l2, l3, n-l3);
              if (cg == 0.0) continue;
              cplx q3c = { q3.re, -q3.im };
              cplx term = cmul(q12, q3c);
              acc.re += term.re * cg;
              acc.im += term.im * cg;
            }
          }
        }
        const double w = acc.re / sqrt((double)(2*l3+1));  // su2_cg's 1/sqrt(2l3+1)
        val = (float)(w * 0.10540925533894598);            // fold 1/sqrt(30)/sqrt(3)
      }
    }
    cw[t] = val;
  }

  // Job B: repack W_chem -> wcB[b][d][k][c] = W_chem[k, d*192 + 3c + b]
  const int tb = t - CW_FLOATS;
  if (tb >= 0 && tb < WCB_FLOATS){
    const int c = tb & 63;
    const int k = (tb >> 6) % 30;
    const int d = (tb / 1920) % 9;
    const int b = tb / 17280;
    wcB[tb] = W_chem[k*1728 + d*192 + 3*c + b];
  }

  // Job C: scrambled chem rows, padded to 32 floats/node for scalar loads
  const int tc = t - (CW_FLOATS + WCB_FLOATS);
  if (tc >= 0 && tc < NAB_FLOATS){
    const int n = tc >> 5;
    const int k = tc & 31;
    float v = 0.0f;
    if (k < 30){
      const int i = 30*n + k;
      v = node_attr[(i % N_NODES)*10 + ((i / N_NODES) % 10)];
    }
    nab[tc] = v;
  }
}

// ---------------------------------------------------------------------------
// Main kernel: 256 threads = 4 waves; each wave owns 4 nodes; each thread owns
// one channel c (all 3 body orders fused -> output written directly, no
// cross-thread reduction, no LDS, no barriers). nab/cw/wbody are wave-uniform
// -> SGPR loads; wcB reads are 256 B/wave coalesced and L1-resident.
// ---------------------------------------------------------------------------
template<int dL>
__device__ inline void nn3b_step(const float* __restrict__ wcb_b,
                                 const float* __restrict__ nab_base,
                                 const float* __restrict__ cw,
                                 int c, float wb,
                                 const float (&v)[4][9], float (&o)[4][9])
{
  float u[4] = {0.f, 0.f, 0.f, 0.f};
  const float* wp = wcb_b + dL*(30*64) + c;
  #pragma unroll
  for (int k = 0; k < 30; ++k){
    const float w = wp[k*64];
    #pragma unroll
    for (int l = 0; l < 4; ++l)
      u[l] = fmaf(nab_base[l*32 + k], w, u[l]);
  }
  #pragma unroll
  for (int l = 0; l < 4; ++l) u[l] *= wb;
  #pragma unroll
  for (int e = ENT_OFF[dL]; e < ENT_OFF[dL+1]; ++e){
    const float cc = cw[(dL*9 + ENT_M[e])*9 + ENT_S[e]];
    #pragma unroll
    for (int l = 0; l < 4; ++l)
      o[l][ENT_S[e]] = fmaf(cc * u[l], v[l][ENT_M[e]], o[l][ENT_S[e]]);
  }
}

template<int dL>
__device__ inline void nn3b_steps(const float* __restrict__ wcb_b,
                                  const float* __restrict__ nab_base,
                                  const float* __restrict__ cw,
                                  int c, float wb,
                                  const float (&v)[4][9], float (&o)[4][9])
{
  if constexpr (dL < 9){
    nn3b_step<dL>(wcb_b, nab_base, cw, c, wb, v, o);
    nn3b_steps<dL+1>(wcb_b, nab_base, cw, c, wb, v, o);
  }
}

__global__ __launch_bounds__(256, 4)
void nn3b_main_kernel(const float* __restrict__ nbody,
                      const float* __restrict__ wbody,
                      const float* __restrict__ cw,
                      const float* __restrict__ wcB,
                      const float* __restrict__ nab,
                      float* __restrict__ out)
{
  const int c  = threadIdx.x & 63;
  const int g  = __builtin_amdgcn_readfirstlane((int)(threadIdx.x >> 6)); // force SGPR
  const int n0 = blockIdx.x * 16 + g * 4;

  float o[4][9];
  #pragma unroll
  for (int l = 0; l < 4; ++l)
    #pragma unroll
    for (int s = 0; s < 9; ++s) o[l][s] = 0.0f;

  const float* nab_base = nab + (size_t)n0 * 32;

  for (int b = 0; b < 3; ++b){
    const float wb = wbody[b];
    float v[4][9];
    #pragma unroll
    for (int l = 0; l < 4; ++l){
      const float* vp = nbody + ((size_t)b*N_NODES + (n0 + l))*576 + c*9;
      #pragma unroll
      for (int m = 0; m < 9; ++m) v[l][m] = vp[m];
    }
    const float* wcb_b = wcB + b*(9*30*64);
    nn3b_steps<0>(wcb_b, nab_base, cw, c, wb, v, o);
  }

  #pragma unroll
  for (int l = 0; l < 4; ++l){
    float* op = out + (size_t)(n0 + l)*576 + c*9;
    #pragma unroll
    for (int s = 0; s < 9; ++s) op[s] = o[l][s];
  }
}

extern "C" void kernel_launch(void* const* d_in, const int* in_sizes, int n_in,
                              void* d_out, int out_size, void* d_ws, size_t ws_size,
                              hipStream_t stream)
{
  const float* nbody     = (const float*)d_in[0];  // (3, 20000, 64, 9) f32
  const float* node_attr = (const float*)d_in[1];  // (20000, 10) f32
  const float* W_chem    = (const float*)d_in[2];  // (30, 1728) f32
  const float* wbody     = (const float*)d_in[3];  // (3, 1) f32
  float* out = (float*)d_out;                      // (20000, 64, 9) f32

  float* cw  = (float*)d_ws;          // 1024 f
  float* wcB = cw + CW_FLOATS;        // 51840 f
  float* nab = wcB + WCB_FLOATS;      // 640000 f   (total ~2.65 MiB of ws)

  const int init_items  = CW_FLOATS + WCB_FLOATS + NAB_FLOATS;
  const int init_blocks = (init_items + 255) / 256;
  nn3b_init_kernel<<<init_blocks, 256, 0, stream>>>(node_attr, W_chem, cw, wcB, nab);

  nn3b_main_kernel<<<N_NODES/16, 256, 0, stream>>>(nbody, wbody, cw, wcB, nab, out);
}